// Round 6
// baseline (476.572 us; speedup 1.0000x reference)
//
#include <hip/hip_runtime.h>
#include <cstdint>

#define K_SEL 4768
#define CAND_CAP 16384
#define NBIN 4096
#define TPAD 9216   // padded-triangular T words per (img,lvl): 64 * sum((c+1)|1, c=0..15)
#define NBLK 240
#define NTHR 320

struct P5 { const float* p[5]; };

__device__ __forceinline__ unsigned fsortkey(float f) {
  unsigned b = __float_as_uint(f);
  return (b & 0x80000000u) ? ~b : (b | 0x80000000u);
}

// ------- histogram of sortable-logit top-12 bits per (img,lvl): per-block partials ------
// stays a SEPARATE massively-parallel kernel (r5 lesson: 1 block/p serializes reads).
// block (0,0) also zero-inits the gather counters and the grid-barrier counter.
__global__ __launch_bounds__(256) void k_hist(P5 obj, unsigned* phist,
                                              unsigned* cnt, unsigned* bar) {
  if (blockIdx.x == 0 && blockIdx.y == 0 && threadIdx.x < 41) {
    if (threadIdx.x < 40) cnt[threadIdx.x] = 0;
    else bar[0] = 0;
  }
  int p = blockIdx.y; int img = p / 5, lvl = p % 5;
  int f = 256 >> lvl; int n = 3 * f * f;
  __shared__ unsigned lh[NBIN];
  for (int b = threadIdx.x; b < NBIN; b += 256) lh[b] = 0;
  __syncthreads();
  const float4* src4 = (const float4*)(obj.p[lvl] + (size_t)img * n);
  int n4 = n >> 2;
  int chunk = (n4 + gridDim.x - 1) / gridDim.x;
  int e0 = blockIdx.x * chunk, e1 = min(n4, e0 + chunk);
  for (int e = e0 + threadIdx.x; e < e1; e += 256) {
    float4 v = src4[e];
    atomicAdd(&lh[fsortkey(v.x) >> 20], 1u);
    atomicAdd(&lh[fsortkey(v.y) >> 20], 1u);
    atomicAdd(&lh[fsortkey(v.z) >> 20], 1u);
    atomicAdd(&lh[fsortkey(v.w) >> 20], 1u);
  }
  __syncthreads();
  unsigned* dst = phist + ((size_t)(p * 8 + blockIdx.x)) * NBIN;
  for (int b = threadIdx.x; b < NBIN; b += 256) dst[b] = lh[b];
}

// ---------------- IoU on offset boxes, bitwise matching reference -----------------------
__device__ __forceinline__ bool iou_gt(float rx1, float ry1, float rx2, float ry2, float rar,
                                       float cx1, float cy1, float cx2, float cy2, float car) {
  float ltx = fmaxf(rx1, cx1), lty = fmaxf(ry1, cy1);
  float rbx = fminf(rx2, cx2), rby = fminf(ry2, cy2);
  float wx = fmaxf(__fsub_rn(rbx, ltx), 0.0f);
  float wy = fmaxf(__fsub_rn(rby, lty), 0.0f);
  float inter = __fmul_rn(wx, wy);
  float denom = __fadd_rn(__fsub_rn(__fadd_rn(rar, car), inter), 1e-9f);
  return __fdiv_rn(inter, denom) > 0.7f;
}

// ---- software grid barrier: monotonic counter, agent-scope fences ----------------------
// Safe under rocprof kernel replay: stale-high counter values only make the barrier a
// no-op (never a hang). Co-residency argued in launcher comment.
__device__ __forceinline__ void gbar(unsigned* bar, unsigned target) {
  __syncthreads();
  if (threadIdx.x == 0) {
    __threadfence();                          // release: drain + L2 writeback (agent)
    atomicAdd(bar, 1u);                       // device-scope RMW
    while (__hip_atomic_load(bar, __ATOMIC_ACQUIRE, __HIP_MEMORY_SCOPE_AGENT) < target)
      __builtin_amdgcn_s_sleep(2);
    __threadfence();                          // acquire: invalidate caches
  }
  __syncthreads();
}

#define CURW(w) ((c & 1) ? tvB[w] : tvA[w])
#define NXTW(w) ((c & 1) ? tvA[w] : tvB[w])

// ---- MEGA: thresh -> gather -> select -> decode -> lvlmask -> nms+merge ---------------
// Every phase keeps its r4 parallel decomposition (>=6 blocks per p); only the dispatch
// boundaries are replaced by software grid barriers.
__global__ __launch_bounds__(NTHR, 3) void k_mega(
    P5 obj, P5 del, const float* anchors, const unsigned* phist,
    unsigned* cnt, int* Bthr, unsigned long long* candK,
    unsigned* selSV, unsigned* selIdx, float* boxP, unsigned long long* keyP,
    unsigned long long* T, unsigned* bar, float* out) {
  int b = blockIdx.x;
  int tid = threadIdx.x;
  int lane = tid & 63, wv = tid >> 6;
  __shared__ __align__(16) char smem[61056];   // union across phases (max: nms 60,980 B)

  // ===== phase 1: threshold (blocks 0..39 = one per (img,lvl)) =====
  if (b < 40) {
    unsigned* hsum = (unsigned*)smem;          // [4096]
    unsigned* csum = (unsigned*)(smem + 16384);// [256]
    int lvl = b % 5;
    unsigned kk = (lvl == 4) ? 768u : 1000u;
    if (tid < 256) {
      unsigned tot[16];
#pragma unroll
      for (int k = 0; k < 16; ++k) tot[k] = 0;
      for (int g = 0; g < 8; ++g) {
        const unsigned* hp = phist + ((size_t)(b * 8 + g)) * NBIN + tid * 16;
#pragma unroll
        for (int k = 0; k < 16; ++k) tot[k] += hp[k];
      }
      unsigned s = 0;
#pragma unroll
      for (int k = 0; k < 16; ++k) { hsum[tid * 16 + k] = tot[k]; s += tot[k]; }
      csum[tid] = s;
    }
    __syncthreads();
    if (tid == 0) {
      unsigned acc = 0; int B = 0;
      for (int cc = 255; cc >= 0; --cc) {
        if (acc + csum[cc] >= kk) {
          for (int bb = 15; bb >= 0; --bb) {
            acc += hsum[cc * 16 + bb];
            if (acc >= kk) { B = cc * 16 + bb; break; }
          }
          break;
        }
        acc += csum[cc];
      }
      Bthr[b] = B;
    }
  }
  gbar(bar, 1 * NBLK);

  // ===== phase 2: gather (6 blocks per p; leader-ballot atomic, direct global) =====
  {
    int p = b / 6, sub = b - p * 6;
    int img = p / 5, lvl = p % 5;
    int f = 256 >> lvl, hw = f * f, n = 3 * hw;
    int B = Bthr[p];
    int shift = 2 * (8 - lvl);
    const float4* src4 = (const float4*)(obj.p[lvl] + (size_t)img * n);
    int n4 = n >> 2;
    unsigned long long* dstG = candK + (size_t)p * CAND_CAP;
    for (int e = sub * NTHR + tid; e < n4; e += 6 * NTHR) {
      float4 v = src4[e];
      float vv[4] = {v.x, v.y, v.z, v.w};
#pragma unroll
      for (int j = 0; j < 4; ++j) {
        unsigned sv = fsortkey(vv[j]);
        bool pass = (int)(sv >> 20) >= B;
        unsigned long long m = __ballot(pass);
        if (m) {
          int leader = __ffsll(m) - 1;
          unsigned base = 0;
          if (lane == leader) base = atomicAdd(&cnt[p], (unsigned)__popcll(m));
          base = __shfl(base, leader);
          if (pass) {
            unsigned pos = base + (unsigned)__popcll(m & ((1ULL << lane) - 1ULL));
            int ee = e * 4 + j;
            int a = ee >> shift;                 // ee / hw
            int r = ee & (hw - 1);               // ee % hw
            unsigned kidx = (unsigned)(r * 3 + a);
            unsigned long long key = ((unsigned long long)sv << 32) | (0xFFFFFFFFu - kidx);
            if (pos < CAND_CAP) dstG[pos] = key;
          }
        }
      }
    }
  }
  gbar(bar, 2 * NBLK);

  // ===== phase 3: select (6 blocks per p; LDS-staged rank counting) =====
  {
    int p = b / 6, sub = b - p * 6;
    int img = p / 5, lvl = p % 5;
    int kk = (lvl == 4) ? 768 : 1000;
    int soff = lvl * 1000;
    int Cc = min((int)cnt[p], CAND_CAP);
    const unsigned long long* keys = candK + (size_t)p * CAND_CAP;
    unsigned long long* sk = (unsigned long long*)smem;  // [4096]
    int stage = min(Cc, 4096);
    for (int j2 = tid; j2 < stage; j2 += NTHR) sk[j2] = keys[j2];
    __syncthreads();
    for (int c = sub * NTHR + tid; c < Cc; c += 6 * NTHR) {
      unsigned long long kc = keys[c];
      int rank = 0;
#pragma unroll 8
      for (int j2 = 0; j2 < stage; ++j2) rank += (sk[j2] > kc) ? 1 : 0;
      for (int j2 = stage; j2 < Cc; ++j2) rank += (keys[j2] > kc) ? 1 : 0;
      if (rank < kk) {
        int slot = img * K_SEL + soff + rank;
        selSV[slot]  = (unsigned)(kc >> 32);
        selIdx[slot] = 0xFFFFFFFFu - (unsigned)kc;
      }
    }
  }
  gbar(bar, 3 * NBLK);

  // ===== phase 4: decode (grid-stride over 8*K_SEL) =====
  for (int x = b * NTHR + tid; x < 8 * K_SEL; x += NBLK * NTHR) {
    int img = x / K_SEL;
    int i = x - img * K_SEL;
    int lvl = (i < 4000) ? (i / 1000) : 4;
    int f = 256 >> lvl, hw = f * f;
    const int aoffA[5] = {0, 196608, 245760, 258048, 261120};
    int slot = img * K_SEL + i;
    unsigned k = selIdx[slot];
    unsigned sv = selSV[slot];
    int a = (int)(k % 3u); int r = (int)(k / 3u);
    int y = r >> (8 - lvl); int x2i = r & (f - 1);
    const float* dp = del.p[lvl] + (size_t)(img * 12 + a * 4) * hw + (size_t)y * f + x2i;
    float d0 = dp[0], d1 = dp[hw], d2 = dp[2 * hw], d3 = dp[3 * hw];
    const float* ar = anchors + (size_t)(aoffA[lvl] + (int)k) * 4;
    float a0 = ar[0], a1 = ar[1], a2 = ar[2], a3 = ar[3];
    float w = __fsub_rn(a2, a0), h = __fsub_rn(a3, a1);
    float cx = __fadd_rn(a0, __fmul_rn(0.5f, w));
    float cy = __fadd_rn(a1, __fmul_rn(0.5f, h));
    const float CLIP = 4.135166556742356f;     // log(1000/16)
    float dw = fminf(d2, CLIP), dh = fminf(d3, CLIP);
    float pcx = __fadd_rn(__fmul_rn(d0, w), cx);
    float pcy = __fadd_rn(__fmul_rn(d1, h), cy);
    float pw = __fmul_rn(expf(dw), w);
    float ph = __fmul_rn(expf(dh), h);
    float x1 = __fsub_rn(pcx, __fmul_rn(0.5f, pw));
    float y1 = __fsub_rn(pcy, __fmul_rn(0.5f, ph));
    float x2 = __fadd_rn(pcx, __fmul_rn(0.5f, pw));
    float y2 = __fadd_rn(pcy, __fmul_rn(0.5f, ph));
    float x1c = fminf(fmaxf(x1, 0.0f), 1024.0f);
    float y1c = fminf(fmaxf(y1, 0.0f), 1024.0f);
    float x2c = fminf(fmaxf(x2, 0.0f), 1024.0f);
    float y2c = fminf(fmaxf(y2, 0.0f), 1024.0f);
    bool valid = (__fsub_rn(x2c, x1c) >= 1e-3f) && (__fsub_rn(y2c, y1c) >= 1e-3f);
    float* bp = boxP + (size_t)slot * 4;
    bp[0] = x1c; bp[1] = y1c; bp[2] = x2c; bp[3] = y2c;
    unsigned low = 0xFFFFFFFFu - (unsigned)i;
    keyP[slot] = valid ? (((unsigned long long)sv << 32) | low) : (unsigned long long)low;
  }
  gbar(bar, 4 * NBLK);

  // ===== phase 5: lvlmask (4976 64-lane units, 5 units/block, 5 uniform iterations) =====
  {
    float* fb = (float*)smem;                  // [5 units][5 arrays][64]
    const int Pt[16] = {0, 1, 4, 7, 12, 17, 24, 31, 40, 49, 60, 71, 84, 97, 112, 127};
    float* rx1s = fb + (wv * 5 + 0) * 64;
    float* ry1s = fb + (wv * 5 + 1) * 64;
    float* rx2s = fb + (wv * 5 + 2) * 64;
    float* ry2s = fb + (wv * 5 + 3) * 64;
    float* rars = fb + (wv * 5 + 4) * 64;
    for (int it = 0; it < 5; ++it) {
      int unit = it * (NBLK * 5) + b * 5 + wv; // stride 1200, 5 iters cover 4976
      bool act = unit < 4976;
      int img = 0, lvl = 0, rb = 0, cb = 0, kk2 = 1000;
      if (act) {
        img = unit / 622;
        int q = unit - img * 622;
        int q2;
        if (q < 544) { lvl = q / 136; q2 = q - lvl * 136; }
        else         { lvl = 4;       q2 = q - 544; }
        kk2 = (lvl == 4) ? 768 : 1000;
        int nch = (kk2 + 63) >> 6;
        rb = 0;
        while (q2 >= nch - rb) { q2 -= nch - rb; ++rb; }
        cb = rb + q2;
      }
      __syncthreads();                         // prior iter's readers done
      float off = __fmul_rn((float)lvl, 1025.0f);
      const float4* b4 = (const float4*)boxP + (size_t)img * K_SEL + lvl * 1000;
      if (act) {
        int j = rb * 64 + lane;                // ROW box staged in LDS
        if (j < kk2) {
          float4 bb = b4[j];
          float ox1 = __fadd_rn(bb.x, off), oy1 = __fadd_rn(bb.y, off);
          float ox2 = __fadd_rn(bb.z, off), oy2 = __fadd_rn(bb.w, off);
          rx1s[lane] = ox1; ry1s[lane] = oy1; rx2s[lane] = ox2; ry2s[lane] = oy2;
          rars[lane] = __fmul_rn(__fsub_rn(ox2, ox1), __fsub_rn(oy2, oy1));
        }
      }
      __syncthreads();
      if (act) {
        int i = cb * 64 + lane;                // COLUMN box in registers
        if (i < kk2) {
          float4 bb = b4[i];
          float cx1 = __fadd_rn(bb.x, off), cy1 = __fadd_rn(bb.y, off);
          float cx2 = __fadd_rn(bb.z, off), cy2 = __fadd_rn(bb.w, off);
          float car = __fmul_rn(__fsub_rn(cx2, cx1), __fsub_rn(cy2, cy1));
          int jmaxR = min(64, kk2 - rb * 64);
          int jend = (rb == cb) ? min(lane, jmaxR) : jmaxR;
          unsigned long long bits = 0;
          for (int jj = 0; jj < jend; ++jj) {
            if (iou_gt(rx1s[jj], ry1s[jj], rx2s[jj], ry2s[jj], rars[jj],
                       cx1, cy1, cx2, cy2, car))
              bits |= (1ULL << jj);
          }
          int sc = (cb + 1) | 1;
          T[(size_t)(img * 5 + lvl) * TPAD + 64 * Pt[cb] + lane * sc + rb] = bits;
        }
      }
    }
  }
  gbar(bar, 5 * NBLK);

  // ===== phase 6: nms sweep (5 waves = 5 levels) + merge (blocks 0..7 = images) =====
  if (b >= 8) return;
  {
    int img = b;
    unsigned long long* lkey = (unsigned long long*)smem;            // 40000 B
    int* lpos                = (int*)(smem + 40000);                 // 20000 B
    unsigned long long* kwS  = (unsigned long long*)(smem + 60000);  // 640 B
    int (*wp)[17]            = (int(*)[17])(smem + 60640);           // 340 B
    const int Pt[16] = {0, 1, 4, 7, 12, 17, 24, 31, 40, 49, 60, 71, 84, 97, 112, 127};
    {
      int lvl = wv;
      int kk = (lvl == 4) ? 768 : 1000;
      int nch = (kk + 63) >> 6;
      const unsigned long long* Tp = T + (size_t)(img * 5 + lvl) * TPAD;
      const unsigned long long* kp = keyP + (size_t)img * K_SEL + lvl * 1000;
      unsigned vmask = 0;
#pragma unroll
      for (int c = 0; c < 16; ++c) {
        int i = c * 64 + lane;
        bool v = (i < kk) && ((kp[min(i, kk - 1)] >> 32) != 0ULL);
        vmask |= v ? (1u << c) : 0u;
      }
      unsigned long long tvA[16], tvB[16];
      unsigned long long kw0=0,kw1=0,kw2=0,kw3=0,kw4=0,kw5=0,kw6=0,kw7=0,
                         kw8=0,kw9=0,kw10=0,kw11=0,kw12=0,kw13=0,kw14=0,kw15=0;
      tvA[0] = Tp[lane];                       // preload chunk 0
#pragma unroll
      for (int c = 0; c < 16; ++c) {
        if (c < nch) {
          if (c + 1 < nch) {                   // prefetch next chunk
            int nb = 64 * Pt[c + 1] + lane * ((c + 2) | 1);
#pragma unroll
            for (int w = 0; w <= c + 1; ++w) NXTW(w) = Tp[nb + w];
          }
          unsigned long long a = 0;
#pragma unroll
          for (int w = 0; w < c; ++w) {
            unsigned long long kv =
              (w==0)?kw0:(w==1)?kw1:(w==2)?kw2:(w==3)?kw3:(w==4)?kw4:(w==5)?kw5:
              (w==6)?kw6:(w==7)?kw7:(w==8)?kw8:(w==9)?kw9:(w==10)?kw10:(w==11)?kw11:
              (w==12)?kw12:(w==13)?kw13:(w==14)?kw14:kw15;
            a |= CURW(w) & kv;
          }
          unsigned long long colT = CURW(c);
          bool alive = ((vmask >> c) & 1u) && (a == 0ULL);
          unsigned long long keepm = 0ULL;
          unsigned long long actm = __ballot(alive);
          while (actm) {
            bool cank = alive && ((colT & actm) == 0ULL);
            unsigned long long newk = __ballot(cank);
            keepm |= newk;
            alive = alive && !cank && ((colT & newk) == 0ULL);
            actm = __ballot(alive);
          }
          switch (c) {
            case 0: kw0=keepm; break;  case 1: kw1=keepm; break;
            case 2: kw2=keepm; break;  case 3: kw3=keepm; break;
            case 4: kw4=keepm; break;  case 5: kw5=keepm; break;
            case 6: kw6=keepm; break;  case 7: kw7=keepm; break;
            case 8: kw8=keepm; break;  case 9: kw9=keepm; break;
            case 10: kw10=keepm; break; case 11: kw11=keepm; break;
            case 12: kw12=keepm; break; case 13: kw13=keepm; break;
            case 14: kw14=keepm; break; default: kw15=keepm; break;
          }
        }
      }
      if (lane == 0) {
        kwS[lvl*16+0]=kw0;  kwS[lvl*16+1]=kw1;  kwS[lvl*16+2]=kw2;  kwS[lvl*16+3]=kw3;
        kwS[lvl*16+4]=kw4;  kwS[lvl*16+5]=kw5;  kwS[lvl*16+6]=kw6;  kwS[lvl*16+7]=kw7;
        kwS[lvl*16+8]=kw8;  kwS[lvl*16+9]=kw9;  kwS[lvl*16+10]=kw10; kwS[lvl*16+11]=kw11;
        kwS[lvl*16+12]=kw12; kwS[lvl*16+13]=kw13; kwS[lvl*16+14]=kw14; kwS[lvl*16+15]=kw15;
      }
    }
    __syncthreads();
    if (tid < 5) {
      int acc = 0;
      for (int w = 0; w < 16; ++w) { wp[tid][w] = acc; acc += (int)__popcll(kwS[tid*16+w]); }
      wp[tid][16] = acc;
    }
    __syncthreads();
    const unsigned long long* kp = keyP + (size_t)img * K_SEL;
    for (int i = tid; i < K_SEL; i += NTHR) {
      int l = (i < 4000) ? i / 1000 : 4;
      int li = i - l * 1000;
      unsigned long long wmask = kwS[l * 16 + (li >> 6)];
      if ((wmask >> (li & 63)) & 1ULL) {
        int j = wp[l][li >> 6] + (int)__popcll(wmask & ((1ULL << (li & 63)) - 1ULL));
        lkey[l * 1000 + j] = kp[i];
        lpos[l * 1000 + j] = i;
      }
    }
    __syncthreads();
    const float4* b4 = (const float4*)boxP + (size_t)img * K_SEL;
    float4* out4 = (float4*)out + (size_t)img * 1000;
    for (int x = tid; x < 5000; x += NTHR) {
      int l = x / 1000, j = x - l * 1000;
      if (j >= wp[l][16]) continue;
      unsigned long long key = lkey[x];
      int grank = j;
#pragma unroll
      for (int l2 = 0; l2 < 5; ++l2) {
        if (l2 == l) continue;
        int lo = 0, hi = wp[l2][16];
        const unsigned long long* aa = &lkey[l2 * 1000];
        while (lo < hi) { int mid = (lo + hi) >> 1; if (aa[mid] > key) lo = mid + 1; else hi = mid; }
        grank += lo;
      }
      if (grank < 1000) out4[grank] = b4[lpos[x]];
    }
    int KT = wp[0][16] + wp[1][16] + wp[2][16] + wp[3][16] + wp[4][16];
    for (int s = min(KT, 1000) + tid; s < 1000; s += NTHR)
      out4[s] = make_float4(0.f, 0.f, 0.f, 0.f);
  }
}

extern "C" void kernel_launch(void* const* d_in, const int* in_sizes, int n_in,
                              void* d_out, int out_size, void* d_ws, size_t ws_size,
                              hipStream_t stream) {
  (void)in_sizes; (void)n_in;
  P5 obj, del;
  for (int i = 0; i < 5; ++i) {
    obj.p[i] = (const float*)d_in[2 * i];
    del.p[i] = (const float*)d_in[2 * i + 1];
  }
  const float* anchors = (const float*)d_in[10];
  float* out = (float*)d_out;
  char* ws = (char*)d_ws;

  // ws layout (bytes)
  unsigned* cnt               = (unsigned*)(ws + 0);                   // 160
  int* Bthr                   = (int*)(ws + 192);                      // 160
  unsigned* bar               = (unsigned*)(ws + 384);                 // 4
  unsigned long long* candK   = (unsigned long long*)(ws + 512);       // 5242880 -> 5243392
  unsigned* selSV             = (unsigned*)(ws + 5243392);             // 152576 -> 5395968
  unsigned* selIdx            = (unsigned*)(ws + 5395968);             // 152576 -> 5548544
  float* boxP                 = (float*)(ws + 5548544);                // 610304 -> 6158848
  unsigned long long* keyP    = (unsigned long long*)(ws + 6158848);   // 305152 -> 6464000
  unsigned long long* T       = (unsigned long long*)(ws + 6469120);   // 2949120 -> 9418240
  unsigned* phist             = (unsigned*)(ws + 6469120);             // overlay on T (dead before lvlmask phase)
  const size_t NEED = 11712000ULL;
  if (ws_size < NEED) { hipMemsetAsync(d_out, 0, (size_t)out_size * 4, stream); return; }

  // Co-residency for the software grid barrier: 240 blocks <= 256 CUs; worst-case packing
  // needs 2 blocks/CU = 10 waves/CU (launch_bounds(320,3) caps VGPR for 3 waves/SIMD) and
  // 2 x 61056 B LDS = 122 KiB <= 160 KiB. All 240 blocks are schedulable simultaneously.
  k_hist <<<dim3(8, 40), 256, 0, stream>>>(obj, phist, cnt, bar);
  k_mega <<<NBLK, NTHR, 0, stream>>>(obj, del, anchors, phist, cnt, Bthr, candK,
                                     selSV, selIdx, boxP, keyP, T, bar, out);
}

// Round 7
// 248.192 us; speedup vs baseline: 1.9202x; 1.9202x over previous
//
#include <hip/hip_runtime.h>
#include <cstdint>

#define K_SEL 4768
#define NBIN 4096
#define BUFCAP 512
#define SLICE 512
#define TPAD 9216   // padded-triangular T words per (img,lvl): 64 * sum((c+1)|1, c=0..15)

struct P5 { const float* p[5]; };

__device__ __forceinline__ unsigned fsortkey(float f) {
  unsigned b = __float_as_uint(f);
  return (b & 0x80000000u) ? ~b : (b | 0x80000000u);
}

// ------- histogram of sortable-logit top-12 bits per (img,lvl): per-block partials ------
__global__ __launch_bounds__(256) void k_hist(P5 obj, unsigned* phist) {
  int p = blockIdx.y; int img = p / 5, lvl = p % 5;
  int f = 256 >> lvl; int n = 3 * f * f;
  __shared__ unsigned lh[NBIN];
  for (int b = threadIdx.x; b < NBIN; b += 256) lh[b] = 0;
  __syncthreads();
  const float4* src4 = (const float4*)(obj.p[lvl] + (size_t)img * n);
  int n4 = n >> 2;
  int chunk = (n4 + gridDim.x - 1) / gridDim.x;
  int e0 = blockIdx.x * chunk, e1 = min(n4, e0 + chunk);
  for (int e = e0 + threadIdx.x; e < e1; e += 256) {
    float4 v = src4[e];
    atomicAdd(&lh[fsortkey(v.x) >> 20], 1u);
    atomicAdd(&lh[fsortkey(v.y) >> 20], 1u);
    atomicAdd(&lh[fsortkey(v.z) >> 20], 1u);
    atomicAdd(&lh[fsortkey(v.w) >> 20], 1u);
  }
  __syncthreads();
  unsigned* dst = phist + ((size_t)(p * 8 + blockIdx.x)) * NBIN;
  for (int b = threadIdx.x; b < NBIN; b += 256) dst[b] = lh[b];   // unconditional: no pre-zero
}

// ------- gather: 32 blocks per p; each block recomputes B (redundant, L2-hit) and -------
// ------- writes its own 512-key slice + plain-store count. NO global atomics, NO init. --
__global__ __launch_bounds__(256) void k_gather(P5 obj, const unsigned* phist,
                                                unsigned* cntB, unsigned long long* ck) {
  int p = blockIdx.y; int img = p / 5, lvl = p % 5;
  int f = 256 >> lvl; int hw = f * f; int n = 3 * hw;
  unsigned kk = (lvl == 4) ? 768u : 1000u;
  int tid = threadIdx.x;
  int lane = tid & 63, wv = tid >> 6;
  __shared__ unsigned hsum[NBIN];
  __shared__ unsigned csum[256];
  __shared__ int Bs;
  // ---- recompute threshold B from phist (each block; ~2 us, all L2 hits) ----
  {
    unsigned tot[16];
#pragma unroll
    for (int k = 0; k < 16; ++k) tot[k] = 0;
    for (int g = 0; g < 8; ++g) {
      const unsigned* hp = phist + ((size_t)(p * 8 + g)) * NBIN + tid * 16;
#pragma unroll
      for (int k = 0; k < 16; ++k) tot[k] += hp[k];
    }
    unsigned s = 0;
#pragma unroll
    for (int k = 0; k < 16; ++k) { hsum[tid * 16 + k] = tot[k]; s += tot[k]; }
    csum[tid] = s;
    __syncthreads();
    if (tid == 0) {
      unsigned acc = 0; int B = 0;
      for (int cc = 255; cc >= 0; --cc) {
        if (acc + csum[cc] >= kk) {
          for (int b = 15; b >= 0; --b) {
            acc += hsum[cc * 16 + b];
            if (acc >= kk) { B = cc * 16 + b; break; }
          }
          break;
        }
        acc += csum[cc];
      }
      Bs = B;
    }
    __syncthreads();
  }
  int B = Bs;
  // ---- gather this block's contiguous chunk into wave-local LDS buffers ----
  int shift = 2 * (8 - lvl);
  const float4* src4 = (const float4*)(obj.p[lvl] + (size_t)img * n);
  int n4 = n >> 2;
  int chunk = (n4 + 31) >> 5;                  // gridDim.x == 32
  int e0 = blockIdx.x * chunk, e1 = min(n4, e0 + chunk);
  __shared__ unsigned long long buf[4][BUFCAP];
  __shared__ unsigned wTot[4];
  unsigned wc = 0;                             // wave-uniform running count
  for (int e = e0 + tid; e < e1; e += 256) {
    float4 v = src4[e];
    float vv[4] = {v.x, v.y, v.z, v.w};
#pragma unroll
    for (int j = 0; j < 4; ++j) {
      unsigned sv = fsortkey(vv[j]);
      bool pass = (int)(sv >> 20) >= B;
      unsigned long long m = __ballot(pass);
      if (m) {
        if (pass) {
          unsigned pos = wc + (unsigned)__popcll(m & ((1ULL << lane) - 1ULL));
          int ee = e * 4 + j;
          int a = ee >> shift;                 // ee / hw
          int r = ee & (hw - 1);               // ee % hw
          unsigned kidx = (unsigned)(r * 3 + a); // reference flatten order (y*W+x)*A + a
          unsigned long long key = ((unsigned long long)sv << 32) | (0xFFFFFFFFu - kidx);
          if (pos < BUFCAP) buf[wv][pos] = key; // overflow (pathological only): drop
        }
        wc += (unsigned)__popcll(m);
      }
    }
  }
  if (lane == 0) wTot[wv] = min(wc, (unsigned)BUFCAP);
  __syncthreads();
  unsigned myOff = 0;
  for (int x = 0; x < wv; ++x) myOff += wTot[x];
  unsigned tot4 = wTot[0] + wTot[1] + wTot[2] + wTot[3];
  unsigned long long* dst = ck + ((size_t)p * 32 + blockIdx.x) * SLICE;
  for (unsigned j = lane; j < wTot[wv]; j += 64) {
    unsigned gp = myOff + j;
    if (gp < SLICE) dst[gp] = buf[wv][j];      // coalesced slice flush, no atomics
  }
  if (tid == 0) cntB[p * 32 + blockIdx.x] = min(tot4, (unsigned)SLICE);
}

// ------- FUSED select+decode: stage compacted slices in LDS, exact rank, decode ---------
__global__ __launch_bounds__(256) void k_seldec(P5 del, const float* anchors,
                                                const unsigned* cntB,
                                                const unsigned long long* ck,
                                                float* boxP, unsigned long long* keyP) {
  int p = blockIdx.y; int img = p / 5, lvl = p % 5;
  int kk = (lvl == 4) ? 768 : 1000;
  int soff = lvl * 1000;
  int tid = threadIdx.x;
  __shared__ unsigned long long sk[4096];
  __shared__ unsigned offs[33];
  if (tid == 0) {
    unsigned acc = 0;
    for (int b2 = 0; b2 < 32; ++b2) { offs[b2] = acc; acc += cntB[p * 32 + b2]; }
    offs[32] = acc;
  }
  __syncthreads();
  int Cc = min((int)offs[32], 4096);
  if (blockIdx.x * 256 >= Cc) return;
  // stage all slices compacted (block-redundant, cheap: Cc ~ 800-1400)
  for (int b2 = 0; b2 < 32; ++b2) {
    unsigned o = offs[b2];
    int c2 = (int)(offs[b2 + 1] - o);
    const unsigned long long* src = ck + ((size_t)p * 32 + b2) * SLICE;
    for (int j = tid; j < c2; j += 256)
      if ((int)(o + j) < 4096) sk[o + j] = src[j];
  }
  __syncthreads();
  int c = blockIdx.x * 256 + tid;
  if (c >= Cc) return;
  unsigned long long kc = sk[c];
  int rank = 0;
#pragma unroll 8
  for (int j = 0; j < Cc; ++j) rank += (sk[j] > kc) ? 1 : 0;
  if (rank >= kk) return;
  // ---- decode inline (numpy-faithful, no FMA contraction) ----
  unsigned k = 0xFFFFFFFFu - (unsigned)kc;
  unsigned sv = (unsigned)(kc >> 32);
  int i = soff + rank;
  int slot = img * K_SEL + i;
  int f = 256 >> lvl, hw = f * f;
  const int aoffA[5] = {0, 196608, 245760, 258048, 261120};
  int a = (int)(k % 3u); int r = (int)(k / 3u);
  int y = r >> (8 - lvl); int x = r & (f - 1);
  const float* dp = del.p[lvl] + (size_t)(img * 12 + a * 4) * hw + (size_t)y * f + x;
  float d0 = dp[0], d1 = dp[hw], d2 = dp[2 * hw], d3 = dp[3 * hw];
  const float* ar = anchors + (size_t)(aoffA[lvl] + (int)k) * 4;
  float a0 = ar[0], a1 = ar[1], a2 = ar[2], a3 = ar[3];
  float w = __fsub_rn(a2, a0), h = __fsub_rn(a3, a1);
  float cx = __fadd_rn(a0, __fmul_rn(0.5f, w));
  float cy = __fadd_rn(a1, __fmul_rn(0.5f, h));
  const float CLIP = 4.135166556742356f;     // log(1000/16)
  float dw = fminf(d2, CLIP), dh = fminf(d3, CLIP);
  float pcx = __fadd_rn(__fmul_rn(d0, w), cx);
  float pcy = __fadd_rn(__fmul_rn(d1, h), cy);
  float pw = __fmul_rn(expf(dw), w);
  float ph = __fmul_rn(expf(dh), h);
  float x1 = __fsub_rn(pcx, __fmul_rn(0.5f, pw));
  float y1 = __fsub_rn(pcy, __fmul_rn(0.5f, ph));
  float x2 = __fadd_rn(pcx, __fmul_rn(0.5f, pw));
  float y2 = __fadd_rn(pcy, __fmul_rn(0.5f, ph));
  float x1c = fminf(fmaxf(x1, 0.0f), 1024.0f);
  float y1c = fminf(fmaxf(y1, 0.0f), 1024.0f);
  float x2c = fminf(fmaxf(x2, 0.0f), 1024.0f);
  float y2c = fminf(fmaxf(y2, 0.0f), 1024.0f);
  bool valid = (__fsub_rn(x2c, x1c) >= 1e-3f) && (__fsub_rn(y2c, y1c) >= 1e-3f);
  float* bp = boxP + (size_t)slot * 4;
  bp[0] = x1c; bp[1] = y1c; bp[2] = x2c; bp[3] = y2c;
  unsigned low = 0xFFFFFFFFu - (unsigned)i;   // pos asc tie-break, unique keys
  keyP[slot] = valid ? (((unsigned long long)sv << 32) | low) : (unsigned long long)low;
}

// ---------------- IoU on offset boxes, bitwise matching reference -----------------------
__device__ __forceinline__ bool iou_gt(float rx1, float ry1, float rx2, float ry2, float rar,
                                       float cx1, float cy1, float cx2, float cy2, float car) {
  float ltx = fmaxf(rx1, cx1), lty = fmaxf(ry1, cy1);
  float rbx = fminf(rx2, cx2), rby = fminf(ry2, cy2);
  float wx = fmaxf(__fsub_rn(rbx, ltx), 0.0f);
  float wy = fmaxf(__fsub_rn(rby, lty), 0.0f);
  float inter = __fmul_rn(wx, wy);
  float denom = __fadd_rn(__fsub_rn(__fadd_rn(rar, car), inter), 1e-9f);
  return __fdiv_rn(inter, denom) > 0.7f;
}

// ---- TRANSPOSED suppression mask T[i] = "which j<i suppress i", triangular-packed ------
__global__ __launch_bounds__(64) void k_lvlmask(const float* boxP, unsigned long long* T) {
  int img = blockIdx.y;
  int q = blockIdx.x;                        // 0..621 per image
  int lvl, q2;
  if (q < 544) { lvl = q / 136; q2 = q - lvl * 136; }
  else         { lvl = 4;       q2 = q - 544; }
  int kk = (lvl == 4) ? 768 : 1000;
  int nch = (kk + 63) >> 6;
  int rb = 0;
  while (q2 >= nch - rb) { q2 -= nch - rb; ++rb; }    // upper-tri (rb, cb>=rb)
  int cb = rb + q2;
  int t = threadIdx.x;
  float off = __fmul_rn((float)lvl, 1025.0f);
  const float4* b4 = (const float4*)boxP + (size_t)img * K_SEL + lvl * 1000;
  __shared__ float rx1s[64], ry1s[64], rx2s[64], ry2s[64], rars[64];
  int j = rb * 64 + t;                       // ROW box staged in LDS
  if (j < kk) {
    float4 bb = b4[j];
    float ox1 = __fadd_rn(bb.x, off), oy1 = __fadd_rn(bb.y, off);
    float ox2 = __fadd_rn(bb.z, off), oy2 = __fadd_rn(bb.w, off);
    rx1s[t] = ox1; ry1s[t] = oy1; rx2s[t] = ox2; ry2s[t] = oy2;
    rars[t] = __fmul_rn(__fsub_rn(ox2, ox1), __fsub_rn(oy2, oy1));
  }
  __syncthreads();
  int i = cb * 64 + t;                       // COLUMN box in registers
  if (i >= kk) return;
  float4 bb = b4[i];
  float cx1 = __fadd_rn(bb.x, off), cy1 = __fadd_rn(bb.y, off);
  float cx2 = __fadd_rn(bb.z, off), cy2 = __fadd_rn(bb.w, off);
  float car = __fmul_rn(__fsub_rn(cx2, cx1), __fsub_rn(cy2, cy1));
  int jmaxR = min(64, kk - rb * 64);
  int jend = (rb == cb) ? min(t, jmaxR) : jmaxR;      // diag: only rows jj < t
  unsigned long long bits = 0;
  for (int jj = 0; jj < jend; ++jj) {
    if (iou_gt(rx1s[jj], ry1s[jj], rx2s[jj], ry2s[jj], rars[jj], cx1, cy1, cx2, cy2, car))
      bits |= (1ULL << jj);
  }
  const int Pt[16] = {0, 1, 4, 7, 12, 17, 24, 31, 40, 49, 60, 71, 84, 97, 112, 127};
  int sc = (cb + 1) | 1;
  T[(size_t)(img * 5 + lvl) * TPAD + 64 * Pt[cb] + t * sc + rb] = bits;
}

// ---- FUSED: per-level NMS sweep (5 waves, one level each) + per-image merge ------------
#define CURW(w) ((c & 1) ? tvB[w] : tvA[w])
#define NXTW(w) ((c & 1) ? tvA[w] : tvB[w])
__global__ __launch_bounds__(320, 1) void k_nmsmerge(const unsigned long long* keyP,
                                                     const unsigned long long* Tg_,
                                                     const float* boxP, float* out) {
  int img = blockIdx.x;
  int tid = threadIdx.x;
  int lane = tid & 63, wv = tid >> 6;        // wv 0..4 = level
  __shared__ unsigned long long kwS[80];
  __shared__ unsigned long long lkey[5000];  // level l at l*1000: compacted kept keys (desc)
  __shared__ int lpos[5000];                 // original within-image slot
  __shared__ int wp[5][17];
  const int Pt[16] = {0, 1, 4, 7, 12, 17, 24, 31, 40, 49, 60, 71, 84, 97, 112, 127};
  {
    int lvl = wv;
    int kk = (lvl == 4) ? 768 : 1000;
    int nch = (kk + 63) >> 6;
    const unsigned long long* Tp = Tg_ + (size_t)(img * 5 + lvl) * TPAD;
    const unsigned long long* kp = keyP + (size_t)img * K_SEL + lvl * 1000;
    unsigned vmask = 0;
#pragma unroll
    for (int c = 0; c < 16; ++c) {
      int i = c * 64 + lane;
      bool v = (i < kk) && ((kp[min(i, kk - 1)] >> 32) != 0ULL);
      vmask |= v ? (1u << c) : 0u;
    }
    unsigned long long tvA[16], tvB[16];
    unsigned long long kw0=0,kw1=0,kw2=0,kw3=0,kw4=0,kw5=0,kw6=0,kw7=0,
                       kw8=0,kw9=0,kw10=0,kw11=0,kw12=0,kw13=0,kw14=0,kw15=0;
    tvA[0] = Tp[lane];                       // preload chunk 0 (Pt[0]=0, sc=1)
#pragma unroll
    for (int c = 0; c < 16; ++c) {
      if (c < nch) {
        if (c + 1 < nch) {                   // issue next chunk's loads (prefetch)
          int nb = 64 * Pt[c + 1] + lane * ((c + 2) | 1);
#pragma unroll
          for (int w = 0; w <= c + 1; ++w) NXTW(w) = Tp[nb + w];
        }
        unsigned long long a = 0;
#pragma unroll
        for (int w = 0; w < c; ++w) {
          unsigned long long kv =
            (w==0)?kw0:(w==1)?kw1:(w==2)?kw2:(w==3)?kw3:(w==4)?kw4:(w==5)?kw5:
            (w==6)?kw6:(w==7)?kw7:(w==8)?kw8:(w==9)?kw9:(w==10)?kw10:(w==11)?kw11:
            (w==12)?kw12:(w==13)?kw13:(w==14)?kw14:kw15;
          a |= CURW(w) & kv;
        }
        unsigned long long colT = CURW(c);
        bool alive = ((vmask >> c) & 1u) && (a == 0ULL);
        unsigned long long keepm = 0ULL;
        unsigned long long actm = __ballot(alive);
        while (actm) {
          bool cank = alive && ((colT & actm) == 0ULL);  // no alive suppressor below t
          unsigned long long newk = __ballot(cank);
          keepm |= newk;
          alive = alive && !cank && ((colT & newk) == 0ULL);
          actm = __ballot(alive);
        }
        switch (c) {                          // static store of wave-uniform keep word
          case 0: kw0=keepm; break;  case 1: kw1=keepm; break;
          case 2: kw2=keepm; break;  case 3: kw3=keepm; break;
          case 4: kw4=keepm; break;  case 5: kw5=keepm; break;
          case 6: kw6=keepm; break;  case 7: kw7=keepm; break;
          case 8: kw8=keepm; break;  case 9: kw9=keepm; break;
          case 10: kw10=keepm; break; case 11: kw11=keepm; break;
          case 12: kw12=keepm; break; case 13: kw13=keepm; break;
          case 14: kw14=keepm; break; default: kw15=keepm; break;
        }
      }
    }
    if (lane == 0) {
      kwS[lvl*16+0]=kw0;  kwS[lvl*16+1]=kw1;  kwS[lvl*16+2]=kw2;  kwS[lvl*16+3]=kw3;
      kwS[lvl*16+4]=kw4;  kwS[lvl*16+5]=kw5;  kwS[lvl*16+6]=kw6;  kwS[lvl*16+7]=kw7;
      kwS[lvl*16+8]=kw8;  kwS[lvl*16+9]=kw9;  kwS[lvl*16+10]=kw10; kwS[lvl*16+11]=kw11;
      kwS[lvl*16+12]=kw12; kwS[lvl*16+13]=kw13; kwS[lvl*16+14]=kw14; kwS[lvl*16+15]=kw15;
    }
  }
  __syncthreads();
  // ---- merge phase (whole block) ----
  if (tid < 5) {
    int acc = 0;
    for (int w = 0; w < 16; ++w) { wp[tid][w] = acc; acc += (int)__popcll(kwS[tid * 16 + w]); }
    wp[tid][16] = acc;
  }
  __syncthreads();
  const unsigned long long* kp = keyP + (size_t)img * K_SEL;
  for (int i = tid; i < K_SEL; i += 320) {
    int l = (i < 4000) ? i / 1000 : 4;
    int li = i - l * 1000;
    unsigned long long wmask = kwS[l * 16 + (li >> 6)];
    if ((wmask >> (li & 63)) & 1ULL) {
      int j = wp[l][li >> 6] + (int)__popcll(wmask & ((1ULL << (li & 63)) - 1ULL));
      lkey[l * 1000 + j] = kp[i];
      lpos[l * 1000 + j] = i;
    }
  }
  __syncthreads();
  const float4* b4 = (const float4*)boxP + (size_t)img * K_SEL;
  float4* out4 = (float4*)out + (size_t)img * 1000;
  for (int x = tid; x < 5000; x += 320) {
    int l = x / 1000, j = x - l * 1000;
    if (j >= wp[l][16]) continue;
    unsigned long long key = lkey[x];
    int grank = j;
#pragma unroll
    for (int l2 = 0; l2 < 5; ++l2) {
      if (l2 == l) continue;
      int lo = 0, hi = wp[l2][16];
      const unsigned long long* a = &lkey[l2 * 1000];
      while (lo < hi) { int mid = (lo + hi) >> 1; if (a[mid] > key) lo = mid + 1; else hi = mid; }
      grank += lo;                            // count of keys > key in level l2
    }
    if (grank < 1000) out4[grank] = b4[lpos[x]];
  }
  int KT = wp[0][16] + wp[1][16] + wp[2][16] + wp[3][16] + wp[4][16];
  for (int s = min(KT, 1000) + tid; s < 1000; s += 320)
    out4[s] = make_float4(0.f, 0.f, 0.f, 0.f);            // zero-pad tail
}

extern "C" void kernel_launch(void* const* d_in, const int* in_sizes, int n_in,
                              void* d_out, int out_size, void* d_ws, size_t ws_size,
                              hipStream_t stream) {
  (void)in_sizes; (void)n_in;
  // setup_inputs() dict order is INTERLEAVED: obj_l0, delta_l0, obj_l1, delta_l1, ..., anchors
  P5 obj, del;
  for (int i = 0; i < 5; ++i) {
    obj.p[i] = (const float*)d_in[2 * i];
    del.p[i] = (const float*)d_in[2 * i + 1];
  }
  const float* anchors = (const float*)d_in[10];
  float* out = (float*)d_out;
  char* ws = (char*)d_ws;

  // ws layout (bytes) — no counters needing zero-init anywhere
  unsigned* cntB              = (unsigned*)(ws + 0);                   // 40*32*4 = 5120
  unsigned long long* candK   = (unsigned long long*)(ws + 8192);     // 40*32*512*8 = 5242880 -> 5251072
  float* boxP                 = (float*)(ws + 5548544);                // 610304 -> 6158848
  unsigned long long* keyP    = (unsigned long long*)(ws + 6158848);   // 305152 -> 6464000
  unsigned long long* T       = (unsigned long long*)(ws + 6469120);   // 2949120 -> 9418240
  unsigned* phist             = (unsigned*)(ws + 6469120);             // overlay on T (dead before k_lvlmask): 5242880 -> 11712000
  const size_t NEED = 11712000ULL;
  if (ws_size < NEED) { hipMemsetAsync(d_out, 0, (size_t)out_size * 4, stream); return; }

  k_hist     <<<dim3(8, 40), 256, 0, stream>>>(obj, phist);
  k_gather   <<<dim3(32, 40), 256, 0, stream>>>(obj, phist, cntB, candK);
  k_seldec   <<<dim3(16, 40), 256, 0, stream>>>(del, anchors, cntB, candK, boxP, keyP);
  k_lvlmask  <<<dim3(622, 8), 64, 0, stream>>>(boxP, T);
  k_nmsmerge <<<8, 320, 0, stream>>>(keyP, T, boxP, out);
}

// Round 8
// 211.394 us; speedup vs baseline: 2.2544x; 1.1741x over previous
//
#include <hip/hip_runtime.h>
#include <cstdint>

#define K_SEL 4768
#define NBIN 4096
#define BUFCAP 512
#define SLICE 512
#define TPAD 9216   // padded-triangular T words per (img,lvl): 64 * sum((c+1)|1, c=0..15)

struct P5 { const float* p[5]; };

__device__ __forceinline__ unsigned fsortkey(float f) {
  unsigned b = __float_as_uint(f);
  return (b & 0x80000000u) ? ~b : (b | 0x80000000u);
}

// ------- histogram of sortable-logit top-12 bits per (img,lvl): per-block partials ------
__global__ __launch_bounds__(256) void k_hist(P5 obj, unsigned* phist) {
  int p = blockIdx.y; int img = p / 5, lvl = p % 5;
  int f = 256 >> lvl; int n = 3 * f * f;
  __shared__ unsigned lh[NBIN];
  for (int b = threadIdx.x; b < NBIN; b += 256) lh[b] = 0;
  __syncthreads();
  const float4* src4 = (const float4*)(obj.p[lvl] + (size_t)img * n);
  int n4 = n >> 2;
  int chunk = (n4 + gridDim.x - 1) / gridDim.x;
  int e0 = blockIdx.x * chunk, e1 = min(n4, e0 + chunk);
  for (int e = e0 + threadIdx.x; e < e1; e += 256) {
    float4 v = src4[e];
    atomicAdd(&lh[fsortkey(v.x) >> 20], 1u);
    atomicAdd(&lh[fsortkey(v.y) >> 20], 1u);
    atomicAdd(&lh[fsortkey(v.z) >> 20], 1u);
    atomicAdd(&lh[fsortkey(v.w) >> 20], 1u);
  }
  __syncthreads();
  unsigned* dst = phist + ((size_t)(p * 8 + blockIdx.x)) * NBIN;
  for (int b = threadIdx.x; b < NBIN; b += 256) dst[b] = lh[b];   // unconditional: no pre-zero
}

// ------- sum partials, find threshold bin B (count(bin >= B) >= kk) --------------------
__global__ __launch_bounds__(256) void k_thresh(const unsigned* phist, int* Bthr) {
  int p = blockIdx.x; int lvl = p % 5;
  unsigned kk = (lvl == 4) ? 768u : 1000u;
  __shared__ unsigned hsum[NBIN];
  __shared__ unsigned csum[256];
  int c = threadIdx.x;
  unsigned tot[16];
#pragma unroll
  for (int k = 0; k < 16; ++k) tot[k] = 0;
  for (int g = 0; g < 8; ++g) {
    const unsigned* hp = phist + ((size_t)(p * 8 + g)) * NBIN + c * 16;
#pragma unroll
    for (int k = 0; k < 16; ++k) tot[k] += hp[k];
  }
  unsigned s = 0;
#pragma unroll
  for (int k = 0; k < 16; ++k) { hsum[c * 16 + k] = tot[k]; s += tot[k]; }
  csum[c] = s;
  __syncthreads();
  if (c == 0) {
    unsigned acc = 0; int B = 0;
    for (int cc = 255; cc >= 0; --cc) {
      if (acc + csum[cc] >= kk) {
        for (int b = 15; b >= 0; --b) {
          acc += hsum[cc * 16 + b];
          if (acc >= kk) { B = cc * 16 + b; break; }
        }
        break;
      }
      acc += csum[cc];
    }
    Bthr[p] = B;
  }
}

// ------- gather: 32 blocks per p; per-block 512-key slice, plain-store count ------------
// NO global atomics, NO zero-init anywhere (r6 lesson: atomics on the wave critical path
// cost ~300cy each; slice ownership removes them entirely).
__global__ __launch_bounds__(256) void k_gather(P5 obj, const int* Bthr,
                                                unsigned* cntB, unsigned long long* ck) {
  int p = blockIdx.y; int img = p / 5, lvl = p % 5;
  int f = 256 >> lvl; int hw = f * f; int n = 3 * hw;
  int B = Bthr[p];
  int tid = threadIdx.x;
  int lane = tid & 63, wv = tid >> 6;
  int shift = 2 * (8 - lvl);
  const float4* src4 = (const float4*)(obj.p[lvl] + (size_t)img * n);
  int n4 = n >> 2;
  int chunk = (n4 + 31) >> 5;                  // gridDim.x == 32
  int e0 = blockIdx.x * chunk, e1 = min(n4, e0 + chunk);
  __shared__ unsigned long long buf[4][BUFCAP];
  __shared__ unsigned wTot[4];
  unsigned wc = 0;                             // wave-uniform running count
  for (int e = e0 + tid; e < e1; e += 256) {
    float4 v = src4[e];
    float vv[4] = {v.x, v.y, v.z, v.w};
#pragma unroll
    for (int j = 0; j < 4; ++j) {
      unsigned sv = fsortkey(vv[j]);
      bool pass = (int)(sv >> 20) >= B;
      unsigned long long m = __ballot(pass);
      if (m) {
        if (pass) {
          unsigned pos = wc + (unsigned)__popcll(m & ((1ULL << lane) - 1ULL));
          int ee = e * 4 + j;
          int a = ee >> shift;                 // ee / hw
          int r = ee & (hw - 1);               // ee % hw
          unsigned kidx = (unsigned)(r * 3 + a); // reference flatten order (y*W+x)*A + a
          unsigned long long key = ((unsigned long long)sv << 32) | (0xFFFFFFFFu - kidx);
          if (pos < BUFCAP) buf[wv][pos] = key; // overflow (pathological only): drop
        }
        wc += (unsigned)__popcll(m);
      }
    }
  }
  if (lane == 0) wTot[wv] = min(wc, (unsigned)BUFCAP);
  __syncthreads();
  unsigned myOff = 0;
  for (int x = 0; x < wv; ++x) myOff += wTot[x];
  unsigned tot4 = wTot[0] + wTot[1] + wTot[2] + wTot[3];
  unsigned long long* dst = ck + ((size_t)p * 32 + blockIdx.x) * SLICE;
  for (unsigned j = lane; j < wTot[wv]; j += 64) {
    unsigned gp = myOff + j;
    if (gp < SLICE) dst[gp] = buf[wv][j];      // coalesced slice flush, no atomics
  }
  if (tid == 0) cntB[p * 32 + blockIdx.x] = min(tot4, (unsigned)SLICE);
}

// ------- FUSED select+decode: stage compacted slices in LDS, exact rank, decode ---------
__global__ __launch_bounds__(256) void k_seldec(P5 del, const float* anchors,
                                                const unsigned* cntB,
                                                const unsigned long long* ck,
                                                float* boxP, unsigned long long* keyP) {
  int p = blockIdx.y; int img = p / 5, lvl = p % 5;
  int kk = (lvl == 4) ? 768 : 1000;
  int soff = lvl * 1000;
  int tid = threadIdx.x;
  __shared__ unsigned long long sk[4096];
  __shared__ unsigned offs[33];
  if (tid < 32) {                              // wave-parallel prefix of slice counts
    unsigned v = cntB[p * 32 + tid];
#pragma unroll
    for (int d = 1; d < 32; d <<= 1) {
      unsigned o = __shfl(v, tid - d);
      if (tid >= d) v += o;
    }
    offs[tid + 1] = v;
    if (tid == 0) offs[0] = 0;
  }
  __syncthreads();
  int Cc = min((int)offs[32], 4096);
  if (blockIdx.x * 256 >= Cc) return;
  // stage all slices compacted (block-redundant, cheap: Cc ~ 800-2000, L2-hit)
  for (int b2 = 0; b2 < 32; ++b2) {
    unsigned o = offs[b2];
    int c2 = (int)(offs[b2 + 1] - o);
    const unsigned long long* src = ck + ((size_t)p * 32 + b2) * SLICE;
    for (int j = tid; j < c2; j += 256)
      if ((int)(o + j) < 4096) sk[o + j] = src[j];
  }
  __syncthreads();
  int c = blockIdx.x * 256 + tid;
  if (c >= Cc) return;
  unsigned long long kc = sk[c];
  int rank = 0;
#pragma unroll 8
  for (int j = 0; j < Cc; ++j) rank += (sk[j] > kc) ? 1 : 0;
  if (rank >= kk) return;
  // ---- decode inline (numpy-faithful, no FMA contraction) ----
  unsigned k = 0xFFFFFFFFu - (unsigned)kc;
  unsigned sv = (unsigned)(kc >> 32);
  int i = soff + rank;
  int slot = img * K_SEL + i;
  int f = 256 >> lvl, hw = f * f;
  const int aoffA[5] = {0, 196608, 245760, 258048, 261120};
  int a = (int)(k % 3u); int r = (int)(k / 3u);
  int y = r >> (8 - lvl); int x = r & (f - 1);
  const float* dp = del.p[lvl] + (size_t)(img * 12 + a * 4) * hw + (size_t)y * f + x;
  float d0 = dp[0], d1 = dp[hw], d2 = dp[2 * hw], d3 = dp[3 * hw];
  const float* ar = anchors + (size_t)(aoffA[lvl] + (int)k) * 4;
  float a0 = ar[0], a1 = ar[1], a2 = ar[2], a3 = ar[3];
  float w = __fsub_rn(a2, a0), h = __fsub_rn(a3, a1);
  float cx = __fadd_rn(a0, __fmul_rn(0.5f, w));
  float cy = __fadd_rn(a1, __fmul_rn(0.5f, h));
  const float CLIP = 4.135166556742356f;     // log(1000/16)
  float dw = fminf(d2, CLIP), dh = fminf(d3, CLIP);
  float pcx = __fadd_rn(__fmul_rn(d0, w), cx);
  float pcy = __fadd_rn(__fmul_rn(d1, h), cy);
  float pw = __fmul_rn(expf(dw), w);
  float ph = __fmul_rn(expf(dh), h);
  float x1 = __fsub_rn(pcx, __fmul_rn(0.5f, pw));
  float y1 = __fsub_rn(pcy, __fmul_rn(0.5f, ph));
  float x2 = __fadd_rn(pcx, __fmul_rn(0.5f, pw));
  float y2 = __fadd_rn(pcy, __fmul_rn(0.5f, ph));
  float x1c = fminf(fmaxf(x1, 0.0f), 1024.0f);
  float y1c = fminf(fmaxf(y1, 0.0f), 1024.0f);
  float x2c = fminf(fmaxf(x2, 0.0f), 1024.0f);
  float y2c = fminf(fmaxf(y2, 0.0f), 1024.0f);
  bool valid = (__fsub_rn(x2c, x1c) >= 1e-3f) && (__fsub_rn(y2c, y1c) >= 1e-3f);
  float* bp = boxP + (size_t)slot * 4;
  bp[0] = x1c; bp[1] = y1c; bp[2] = x2c; bp[3] = y2c;
  unsigned low = 0xFFFFFFFFu - (unsigned)i;   // pos asc tie-break, unique keys
  keyP[slot] = valid ? (((unsigned long long)sv << 32) | low) : (unsigned long long)low;
}

// ---------------- IoU on offset boxes, bitwise matching reference -----------------------
__device__ __forceinline__ bool iou_gt(float rx1, float ry1, float rx2, float ry2, float rar,
                                       float cx1, float cy1, float cx2, float cy2, float car) {
  float ltx = fmaxf(rx1, cx1), lty = fmaxf(ry1, cy1);
  float rbx = fminf(rx2, cx2), rby = fminf(ry2, cy2);
  float wx = fmaxf(__fsub_rn(rbx, ltx), 0.0f);
  float wy = fmaxf(__fsub_rn(rby, lty), 0.0f);
  float inter = __fmul_rn(wx, wy);
  float denom = __fadd_rn(__fsub_rn(__fadd_rn(rar, car), inter), 1e-9f);
  return __fdiv_rn(inter, denom) > 0.7f;
}

// ---- TRANSPOSED suppression mask T[i] = "which j<i suppress i", triangular-packed ------
__global__ __launch_bounds__(64) void k_lvlmask(const float* boxP, unsigned long long* T) {
  int img = blockIdx.y;
  int q = blockIdx.x;                        // 0..621 per image
  int lvl, q2;
  if (q < 544) { lvl = q / 136; q2 = q - lvl * 136; }
  else         { lvl = 4;       q2 = q - 544; }
  int kk = (lvl == 4) ? 768 : 1000;
  int nch = (kk + 63) >> 6;
  int rb = 0;
  while (q2 >= nch - rb) { q2 -= nch - rb; ++rb; }    // upper-tri (rb, cb>=rb)
  int cb = rb + q2;
  int t = threadIdx.x;
  float off = __fmul_rn((float)lvl, 1025.0f);
  const float4* b4 = (const float4*)boxP + (size_t)img * K_SEL + lvl * 1000;
  __shared__ float rx1s[64], ry1s[64], rx2s[64], ry2s[64], rars[64];
  int j = rb * 64 + t;                       // ROW box staged in LDS
  if (j < kk) {
    float4 bb = b4[j];
    float ox1 = __fadd_rn(bb.x, off), oy1 = __fadd_rn(bb.y, off);
    float ox2 = __fadd_rn(bb.z, off), oy2 = __fadd_rn(bb.w, off);
    rx1s[t] = ox1; ry1s[t] = oy1; rx2s[t] = ox2; ry2s[t] = oy2;
    rars[t] = __fmul_rn(__fsub_rn(ox2, ox1), __fsub_rn(oy2, oy1));
  }
  __syncthreads();
  int i = cb * 64 + t;                       // COLUMN box in registers
  if (i >= kk) return;
  float4 bb = b4[i];
  float cx1 = __fadd_rn(bb.x, off), cy1 = __fadd_rn(bb.y, off);
  float cx2 = __fadd_rn(bb.z, off), cy2 = __fadd_rn(bb.w, off);
  float car = __fmul_rn(__fsub_rn(cx2, cx1), __fsub_rn(cy2, cy1));
  int jmaxR = min(64, kk - rb * 64);
  int jend = (rb == cb) ? min(t, jmaxR) : jmaxR;      // diag: only rows jj < t
  unsigned long long bits = 0;
  for (int jj = 0; jj < jend; ++jj) {
    if (iou_gt(rx1s[jj], ry1s[jj], rx2s[jj], ry2s[jj], rars[jj], cx1, cy1, cx2, cy2, car))
      bits |= (1ULL << jj);
  }
  const int Pt[16] = {0, 1, 4, 7, 12, 17, 24, 31, 40, 49, 60, 71, 84, 97, 112, 127};
  int sc = (cb + 1) | 1;
  T[(size_t)(img * 5 + lvl) * TPAD + 64 * Pt[cb] + t * sc + rb] = bits;
}

// ---- per-level greedy NMS: LDS-staged T + single-wave serial chunk sweep (r4-proven) ---
__global__ __launch_bounds__(256) void k_lvlnms(const unsigned long long* keyP,
                                                const unsigned long long* Tg_,
                                                unsigned long long* keepw) {
  int p = blockIdx.x; int img = p / 5, lvl = p % 5;
  int kk = (lvl == 4) ? 768 : 1000;
  int tw = (lvl == 4) ? 5376 : TPAD;         // words used (lvl4: chunks 0..11 only)
  int tid = threadIdx.x;
  __shared__ __align__(16) unsigned long long Ts[TPAD];   // 72 KiB
  const unsigned long long* Tg = Tg_ + (size_t)p * TPAD;
  const unsigned long long* kp = keyP + (size_t)img * K_SEL + lvl * 1000;
  // wave0: prefetch validity bits for all 16 chunks (overlaps the staging loop's loads)
  unsigned vmask = 0;
  if (tid < 64) {
#pragma unroll
    for (int c = 0; c < 16; ++c) {
      int i = c * 64 + tid;
      bool v = (i < kk) && ((kp[min(i, kk - 1)] >> 32) != 0ULL);
      vmask |= v ? (1u << c) : 0u;
    }
  }
  // staging: x4-batched 16B loads (4 in flight) to hide L2/HBM latency
  {
    const ulonglong2* Tg2 = (const ulonglong2*)Tg;
    ulonglong2* Ts2 = (ulonglong2*)Ts;
    int nv = tw >> 1;
    for (int x = tid; x < nv; x += 1024) {
      int x1i = x + 256, x2i = x + 512, x3i = x + 768;
      ulonglong2 a0 = Tg2[x], a1 = {}, a2 = {}, a3 = {};
      if (x1i < nv) a1 = Tg2[x1i];
      if (x2i < nv) a2 = Tg2[x2i];
      if (x3i < nv) a3 = Tg2[x3i];
      Ts2[x] = a0;
      if (x1i < nv) Ts2[x1i] = a1;
      if (x2i < nv) Ts2[x2i] = a2;
      if (x3i < nv) Ts2[x3i] = a3;
    }
  }
  __syncthreads();
  if (tid >= 64) return;                     // waves 1-3 done (no further barriers)
  int t = tid;
  const int Pt[16] = {0, 1, 4, 7, 12, 17, 24, 31, 40, 49, 60, 71, 84, 97, 112, 127};
  unsigned long long kw[16];
#pragma unroll
  for (int w = 0; w < 16; ++w) kw[w] = 0ULL;
#pragma unroll
  for (int c = 0; c < 16; ++c) {
    if (c * 64 < kk) {
      int base = 64 * Pt[c] + t * ((c + 1) | 1);
      unsigned long long tv[16];
#pragma unroll
      for (int w = 0; w < 16; ++w) tv[w] = Ts[base + w]; // batch reads; w>c garbage, masked
      unsigned long long a = 0;
#pragma unroll
      for (int w = 0; w < 16; ++w) a |= tv[w] & kw[w];   // kw[w]=0 for w>=c
      unsigned long long colT = tv[c];                   // diag word: suppressors j<t in chunk
      bool alive = ((vmask >> c) & 1u) && (a == 0ULL);
      unsigned long long keepm = 0ULL;
      unsigned long long actm = __ballot(alive);
      while (actm) {
        bool cank = alive && ((colT & actm) == 0ULL);    // no alive suppressor below t
        unsigned long long newk = __ballot(cank);
        keepm |= newk;
        alive = alive && !cank && ((colT & newk) == 0ULL);
        actm = __ballot(alive);
      }
      kw[c] = keepm;                                     // static index (unrolled)
    }
  }
  if (t == 0) {
#pragma unroll
    for (int c = 0; c < 16; ++c) keepw[(size_t)p * 16 + c] = kw[c];  // uniform ballot values
  }
}

// ---- merge: 40 blocks = (img,lvl); each compacts all levels (coalesced) but ranks only
// ---- its own level's kept entries (4 interleaved binary searches, short LDS chains) ----
__global__ __launch_bounds__(256) void k_merge(const unsigned long long* keyP, const float* boxP,
                                               const unsigned long long* keepw, float* out) {
  int p = blockIdx.x; int img = p / 5, lvl = p % 5;
  int tid = threadIdx.x;
  __shared__ unsigned long long lkey[5000];   // level l at l*1000: compacted kept keys (desc)
  __shared__ int lpos[5000];                  // original within-image slot
  __shared__ int wp[5][17];                   // per-level word-prefix popcounts
  __shared__ unsigned long long kwS[80];
  for (int x = tid; x < 80; x += 256) {
    kwS[x] = keepw[(size_t)img * 80 + x];     // all 16 words written by k_lvlnms
  }
  __syncthreads();
  if (tid < 5) {
    int acc = 0;
    for (int w = 0; w < 16; ++w) { wp[tid][w] = acc; acc += (int)__popcll(kwS[tid * 16 + w]); }
    wp[tid][16] = acc;
  }
  __syncthreads();
  const unsigned long long* kp = keyP + (size_t)img * K_SEL;
  for (int i = tid; i < K_SEL; i += 256) {
    int l = (i < 4000) ? i / 1000 : 4;
    int li = i - l * 1000;
    unsigned long long wmask = kwS[l * 16 + (li >> 6)];
    if ((wmask >> (li & 63)) & 1ULL) {
      int j = wp[l][li >> 6] + (int)__popcll(wmask & ((1ULL << (li & 63)) - 1ULL));
      lkey[l * 1000 + j] = kp[i];
      lpos[l * 1000 + j] = i;
    }
  }
  __syncthreads();
  const float4* b4 = (const float4*)boxP + (size_t)img * K_SEL;
  float4* out4 = (float4*)out + (size_t)img * 1000;
  int kn = wp[lvl][16];
  for (int j = tid; j < kn; j += 256) {
    unsigned long long key = lkey[lvl * 1000 + j];
    int grank = j;
#pragma unroll
    for (int l2 = 0; l2 < 5; ++l2) {
      if (l2 == lvl) continue;
      int lo = 0, hi = wp[l2][16];
      const unsigned long long* a = &lkey[l2 * 1000];
      while (lo < hi) { int mid = (lo + hi) >> 1; if (a[mid] > key) lo = mid + 1; else hi = mid; }
      grank += lo;                            // count of keys > key in level l2
    }
    if (grank < 1000) out4[grank] = b4[lpos[lvl * 1000 + j]];
  }
  if (lvl == 0) {                             // pad region [KT,1000) has no grank: disjoint
    int KT = wp[0][16] + wp[1][16] + wp[2][16] + wp[3][16] + wp[4][16];
    for (int s = min(KT, 1000) + tid; s < 1000; s += 256)
      out4[s] = make_float4(0.f, 0.f, 0.f, 0.f);          // zero-pad tail
  }
}

extern "C" void kernel_launch(void* const* d_in, const int* in_sizes, int n_in,
                              void* d_out, int out_size, void* d_ws, size_t ws_size,
                              hipStream_t stream) {
  (void)in_sizes; (void)n_in;
  // setup_inputs() dict order is INTERLEAVED: obj_l0, delta_l0, obj_l1, delta_l1, ..., anchors
  P5 obj, del;
  for (int i = 0; i < 5; ++i) {
    obj.p[i] = (const float*)d_in[2 * i];
    del.p[i] = (const float*)d_in[2 * i + 1];
  }
  const float* anchors = (const float*)d_in[10];
  float* out = (float*)d_out;
  char* ws = (char*)d_ws;

  // ws layout (bytes) — nothing needs zero-init
  unsigned* cntB              = (unsigned*)(ws + 0);                   // 5120
  int* Bthr                   = (int*)(ws + 5120);                     // 160 -> 5280
  unsigned long long* candK   = (unsigned long long*)(ws + 8192);      // 5242880 -> 5251072
  float* boxP                 = (float*)(ws + 5548544);                // 610304 -> 6158848
  unsigned long long* keyP    = (unsigned long long*)(ws + 6158848);   // 305152 -> 6464000
  unsigned long long* keepw   = (unsigned long long*)(ws + 6464000);   // 5120 -> 6469120
  unsigned long long* T       = (unsigned long long*)(ws + 6469120);   // 2949120 -> 9418240
  unsigned* phist             = (unsigned*)(ws + 6469120);             // overlay on T (dead before k_lvlmask): 5242880 -> 11712000
  const size_t NEED = 11712000ULL;
  if (ws_size < NEED) { hipMemsetAsync(d_out, 0, (size_t)out_size * 4, stream); return; }

  k_hist    <<<dim3(8, 40), 256, 0, stream>>>(obj, phist);
  k_thresh  <<<40, 256, 0, stream>>>(phist, Bthr);
  k_gather  <<<dim3(32, 40), 256, 0, stream>>>(obj, Bthr, cntB, candK);
  k_seldec  <<<dim3(16, 40), 256, 0, stream>>>(del, anchors, cntB, candK, boxP, keyP);
  k_lvlmask <<<dim3(622, 8), 64, 0, stream>>>(boxP, T);
  k_lvlnms  <<<40, 256, 0, stream>>>(keyP, T, keepw);
  k_merge   <<<40, 256, 0, stream>>>(keyP, boxP, keepw, out);
}

// Round 9
// 206.355 us; speedup vs baseline: 2.3095x; 1.0244x over previous
//
#include <hip/hip_runtime.h>
#include <cstdint>

#define K_SEL 4768
#define NBIN 4096
#define BUFCAP 512
#define SLICE 512
#define TPAD 9216   // padded-triangular T words per (img,lvl): 64 * sum((c+1)|1, c=0..15)

struct P5 { const float* p[5]; };

__device__ __forceinline__ unsigned fsortkey(float f) {
  unsigned b = __float_as_uint(f);
  return (b & 0x80000000u) ? ~b : (b | 0x80000000u);
}

// ------- histogram of sortable-logit top-12 bits per (img,lvl): per-block partials ------
__global__ __launch_bounds__(256) void k_hist(P5 obj, unsigned* phist) {
  int p = blockIdx.y; int img = p / 5, lvl = p % 5;
  int f = 256 >> lvl; int n = 3 * f * f;
  __shared__ unsigned lh[NBIN];
  for (int b = threadIdx.x; b < NBIN; b += 256) lh[b] = 0;
  __syncthreads();
  const float4* src4 = (const float4*)(obj.p[lvl] + (size_t)img * n);
  int n4 = n >> 2;
  int chunk = (n4 + gridDim.x - 1) / gridDim.x;
  int e0 = blockIdx.x * chunk, e1 = min(n4, e0 + chunk);
  for (int e = e0 + threadIdx.x; e < e1; e += 256) {
    float4 v = src4[e];
    atomicAdd(&lh[fsortkey(v.x) >> 20], 1u);
    atomicAdd(&lh[fsortkey(v.y) >> 20], 1u);
    atomicAdd(&lh[fsortkey(v.z) >> 20], 1u);
    atomicAdd(&lh[fsortkey(v.w) >> 20], 1u);
  }
  __syncthreads();
  unsigned* dst = phist + ((size_t)(p * 8 + blockIdx.x)) * NBIN;
  for (int b = threadIdx.x; b < NBIN; b += 256) dst[b] = lh[b];   // unconditional: no pre-zero
}

// ------- sum partials, find threshold bin B (count(bin >= B) >= kk) --------------------
__global__ __launch_bounds__(256) void k_thresh(const unsigned* phist, int* Bthr) {
  int p = blockIdx.x; int lvl = p % 5;
  unsigned kk = (lvl == 4) ? 768u : 1000u;
  __shared__ unsigned hsum[NBIN];
  __shared__ unsigned csum[256];
  int c = threadIdx.x;
  unsigned tot[16];
#pragma unroll
  for (int k = 0; k < 16; ++k) tot[k] = 0;
  for (int g = 0; g < 8; ++g) {
    const unsigned* hp = phist + ((size_t)(p * 8 + g)) * NBIN + c * 16;
#pragma unroll
    for (int k = 0; k < 16; ++k) tot[k] += hp[k];
  }
  unsigned s = 0;
#pragma unroll
  for (int k = 0; k < 16; ++k) { hsum[c * 16 + k] = tot[k]; s += tot[k]; }
  csum[c] = s;
  __syncthreads();
  if (c == 0) {
    unsigned acc = 0; int B = 0;
    for (int cc = 255; cc >= 0; --cc) {
      if (acc + csum[cc] >= kk) {
        for (int b = 15; b >= 0; --b) {
          acc += hsum[cc * 16 + b];
          if (acc >= kk) { B = cc * 16 + b; break; }
        }
        break;
      }
      acc += csum[cc];
    }
    Bthr[p] = B;
  }
}

// ------- gather: 32 blocks per p; per-block 512-key slice, plain-store count ------------
// NO global atomics, NO zero-init anywhere (r6 lesson: atomics on the wave critical path
// cost ~300cy each; slice ownership removes them entirely).
__global__ __launch_bounds__(256) void k_gather(P5 obj, const int* Bthr,
                                                unsigned* cntB, unsigned long long* ck) {
  int p = blockIdx.y; int img = p / 5, lvl = p % 5;
  int f = 256 >> lvl; int hw = f * f; int n = 3 * hw;
  int B = Bthr[p];
  int tid = threadIdx.x;
  int lane = tid & 63, wv = tid >> 6;
  int shift = 2 * (8 - lvl);
  const float4* src4 = (const float4*)(obj.p[lvl] + (size_t)img * n);
  int n4 = n >> 2;
  int chunk = (n4 + 31) >> 5;                  // gridDim.x == 32
  int e0 = blockIdx.x * chunk, e1 = min(n4, e0 + chunk);
  __shared__ unsigned long long buf[4][BUFCAP];
  __shared__ unsigned wTot[4];
  unsigned wc = 0;                             // wave-uniform running count
  for (int e = e0 + tid; e < e1; e += 256) {
    float4 v = src4[e];
    float vv[4] = {v.x, v.y, v.z, v.w};
#pragma unroll
    for (int j = 0; j < 4; ++j) {
      unsigned sv = fsortkey(vv[j]);
      bool pass = (int)(sv >> 20) >= B;
      unsigned long long m = __ballot(pass);
      if (m) {
        if (pass) {
          unsigned pos = wc + (unsigned)__popcll(m & ((1ULL << lane) - 1ULL));
          int ee = e * 4 + j;
          int a = ee >> shift;                 // ee / hw
          int r = ee & (hw - 1);               // ee % hw
          unsigned kidx = (unsigned)(r * 3 + a); // reference flatten order (y*W+x)*A + a
          unsigned long long key = ((unsigned long long)sv << 32) | (0xFFFFFFFFu - kidx);
          if (pos < BUFCAP) buf[wv][pos] = key; // overflow (pathological only): drop
        }
        wc += (unsigned)__popcll(m);
      }
    }
  }
  if (lane == 0) wTot[wv] = min(wc, (unsigned)BUFCAP);
  __syncthreads();
  unsigned myOff = 0;
  for (int x = 0; x < wv; ++x) myOff += wTot[x];
  unsigned tot4 = wTot[0] + wTot[1] + wTot[2] + wTot[3];
  unsigned long long* dst = ck + ((size_t)p * 32 + blockIdx.x) * SLICE;
  for (unsigned j = lane; j < wTot[wv]; j += 64) {
    unsigned gp = myOff + j;
    if (gp < SLICE) dst[gp] = buf[wv][j];      // coalesced slice flush, no atomics
  }
  if (tid == 0) cntB[p * 32 + blockIdx.x] = min(tot4, (unsigned)SLICE);
}

// ------- FUSED select+decode: parallel one-pass staging, prefetch-then-rank -------------
// Staging: each thread finds its candidate's slice via 5-step LDS binary search -> ALL
// loads issue concurrently (was: 32 serial slice loops x ~600cy L3 latency).
// Rank: delta/anchor loads depend only on the key, not the rank -> issue them BEFORE the
// ~Cc-iteration LDS rank scan; their scattered-HBM latency hides under the scan.
__global__ __launch_bounds__(256) void k_seldec(P5 del, const float* anchors,
                                                const unsigned* cntB,
                                                const unsigned long long* ck,
                                                float* boxP, unsigned long long* keyP) {
  int p = blockIdx.y; int img = p / 5, lvl = p % 5;
  int kk = (lvl == 4) ? 768 : 1000;
  int soff = lvl * 1000;
  int tid = threadIdx.x;
  __shared__ unsigned long long sk[4096];
  __shared__ unsigned offs[33];
  if (tid < 32) {                              // wave-parallel prefix of slice counts
    unsigned v = cntB[p * 32 + tid];
#pragma unroll
    for (int d = 1; d < 32; d <<= 1) {
      unsigned o = __shfl(v, tid - d);
      if (tid >= d) v += o;
    }
    offs[tid + 1] = v;
    if (tid == 0) offs[0] = 0;
  }
  __syncthreads();
  int Cc = min((int)offs[32], 4096);
  if (blockIdx.x * 256 >= Cc) return;
  // ---- parallel staging: one load per candidate, all in flight ----
  for (int x = tid; x < Cc; x += 256) {
    int lo = 0;                                // largest lo in [0,31] with offs[lo] <= x
#pragma unroll
    for (int d = 16; d; d >>= 1)
      if (offs[lo + d] <= (unsigned)x) lo += d;
    sk[x] = ck[((size_t)p * 32 + lo) * SLICE + (x - offs[lo])];
  }
  __syncthreads();
  int c = blockIdx.x * 256 + tid;
  if (c >= Cc) return;
  unsigned long long kc = sk[c];
  // ---- prefetch decode inputs (scattered, cold HBM) before the rank scan ----
  unsigned k = 0xFFFFFFFFu - (unsigned)kc;
  unsigned sv = (unsigned)(kc >> 32);
  int f = 256 >> lvl, hw = f * f;
  const int aoffA[5] = {0, 196608, 245760, 258048, 261120};
  int a = (int)(k % 3u); int r = (int)(k / 3u);
  int y = r >> (8 - lvl); int x = r & (f - 1);
  const float* dp = del.p[lvl] + (size_t)(img * 12 + a * 4) * hw + (size_t)y * f + x;
  float d0 = dp[0], d1 = dp[hw], d2 = dp[2 * hw], d3 = dp[3 * hw];
  const float* ar = anchors + (size_t)(aoffA[lvl] + (int)k) * 4;
  float a0 = ar[0], a1 = ar[1], a2 = ar[2], a3 = ar[3];
  // ---- rank scan (LDS broadcast); HBM latency of the loads above hides under it ----
  int rank = 0;
#pragma unroll 8
  for (int j = 0; j < Cc; ++j) rank += (sk[j] > kc) ? 1 : 0;
  if (rank >= kk) return;
  // ---- decode (numpy-faithful, no FMA contraction) ----
  int i = soff + rank;
  int slot = img * K_SEL + i;
  float w = __fsub_rn(a2, a0), h = __fsub_rn(a3, a1);
  float cx = __fadd_rn(a0, __fmul_rn(0.5f, w));
  float cy = __fadd_rn(a1, __fmul_rn(0.5f, h));
  const float CLIP = 4.135166556742356f;     // log(1000/16)
  float dw = fminf(d2, CLIP), dh = fminf(d3, CLIP);
  float pcx = __fadd_rn(__fmul_rn(d0, w), cx);
  float pcy = __fadd_rn(__fmul_rn(d1, h), cy);
  float pw = __fmul_rn(expf(dw), w);
  float ph = __fmul_rn(expf(dh), h);
  float x1 = __fsub_rn(pcx, __fmul_rn(0.5f, pw));
  float y1 = __fsub_rn(pcy, __fmul_rn(0.5f, ph));
  float x2 = __fadd_rn(pcx, __fmul_rn(0.5f, pw));
  float y2 = __fadd_rn(pcy, __fmul_rn(0.5f, ph));
  float x1c = fminf(fmaxf(x1, 0.0f), 1024.0f);
  float y1c = fminf(fmaxf(y1, 0.0f), 1024.0f);
  float x2c = fminf(fmaxf(x2, 0.0f), 1024.0f);
  float y2c = fminf(fmaxf(y2, 0.0f), 1024.0f);
  bool valid = (__fsub_rn(x2c, x1c) >= 1e-3f) && (__fsub_rn(y2c, y1c) >= 1e-3f);
  float* bp = boxP + (size_t)slot * 4;
  bp[0] = x1c; bp[1] = y1c; bp[2] = x2c; bp[3] = y2c;
  unsigned low = 0xFFFFFFFFu - (unsigned)i;   // pos asc tie-break, unique keys
  keyP[slot] = valid ? (((unsigned long long)sv << 32) | low) : (unsigned long long)low;
}

// ---------------- IoU on offset boxes, bitwise matching reference -----------------------
__device__ __forceinline__ bool iou_gt(float rx1, float ry1, float rx2, float ry2, float rar,
                                       float cx1, float cy1, float cx2, float cy2, float car) {
  float ltx = fmaxf(rx1, cx1), lty = fmaxf(ry1, cy1);
  float rbx = fminf(rx2, cx2), rby = fminf(ry2, cy2);
  float wx = fmaxf(__fsub_rn(rbx, ltx), 0.0f);
  float wy = fmaxf(__fsub_rn(rby, lty), 0.0f);
  float inter = __fmul_rn(wx, wy);
  float denom = __fadd_rn(__fsub_rn(__fadd_rn(rar, car), inter), 1e-9f);
  return __fdiv_rn(inter, denom) > 0.7f;
}

// ---- TRANSPOSED suppression mask T[i] = "which j<i suppress i", triangular-packed ------
__global__ __launch_bounds__(64) void k_lvlmask(const float* boxP, unsigned long long* T) {
  int img = blockIdx.y;
  int q = blockIdx.x;                        // 0..621 per image
  int lvl, q2;
  if (q < 544) { lvl = q / 136; q2 = q - lvl * 136; }
  else         { lvl = 4;       q2 = q - 544; }
  int kk = (lvl == 4) ? 768 : 1000;
  int nch = (kk + 63) >> 6;
  int rb = 0;
  while (q2 >= nch - rb) { q2 -= nch - rb; ++rb; }    // upper-tri (rb, cb>=rb)
  int cb = rb + q2;
  int t = threadIdx.x;
  float off = __fmul_rn((float)lvl, 1025.0f);
  const float4* b4 = (const float4*)boxP + (size_t)img * K_SEL + lvl * 1000;
  __shared__ float rx1s[64], ry1s[64], rx2s[64], ry2s[64], rars[64];
  int j = rb * 64 + t;                       // ROW box staged in LDS
  if (j < kk) {
    float4 bb = b4[j];
    float ox1 = __fadd_rn(bb.x, off), oy1 = __fadd_rn(bb.y, off);
    float ox2 = __fadd_rn(bb.z, off), oy2 = __fadd_rn(bb.w, off);
    rx1s[t] = ox1; ry1s[t] = oy1; rx2s[t] = ox2; ry2s[t] = oy2;
    rars[t] = __fmul_rn(__fsub_rn(ox2, ox1), __fsub_rn(oy2, oy1));
  }
  __syncthreads();
  int i = cb * 64 + t;                       // COLUMN box in registers
  if (i >= kk) return;
  float4 bb = b4[i];
  float cx1 = __fadd_rn(bb.x, off), cy1 = __fadd_rn(bb.y, off);
  float cx2 = __fadd_rn(bb.z, off), cy2 = __fadd_rn(bb.w, off);
  float car = __fmul_rn(__fsub_rn(cx2, cx1), __fsub_rn(cy2, cy1));
  int jmaxR = min(64, kk - rb * 64);
  int jend = (rb == cb) ? min(t, jmaxR) : jmaxR;      // diag: only rows jj < t
  unsigned long long bits = 0;
  for (int jj = 0; jj < jend; ++jj) {
    if (iou_gt(rx1s[jj], ry1s[jj], rx2s[jj], ry2s[jj], rars[jj], cx1, cy1, cx2, cy2, car))
      bits |= (1ULL << jj);
  }
  const int Pt[16] = {0, 1, 4, 7, 12, 17, 24, 31, 40, 49, 60, 71, 84, 97, 112, 127};
  int sc = (cb + 1) | 1;
  T[(size_t)(img * 5 + lvl) * TPAD + 64 * Pt[cb] + t * sc + rb] = bits;
}

// ---- per-level greedy NMS: LDS-staged T + single-wave serial chunk sweep (r4-proven) ---
__global__ __launch_bounds__(256) void k_lvlnms(const unsigned long long* keyP,
                                                const unsigned long long* Tg_,
                                                unsigned long long* keepw) {
  int p = blockIdx.x; int img = p / 5, lvl = p % 5;
  int kk = (lvl == 4) ? 768 : 1000;
  int tw = (lvl == 4) ? 5376 : TPAD;         // words used (lvl4: chunks 0..11 only)
  int tid = threadIdx.x;
  __shared__ __align__(16) unsigned long long Ts[TPAD];   // 72 KiB
  const unsigned long long* Tg = Tg_ + (size_t)p * TPAD;
  const unsigned long long* kp = keyP + (size_t)img * K_SEL + lvl * 1000;
  // wave0: prefetch validity bits for all 16 chunks (overlaps the staging loop's loads)
  unsigned vmask = 0;
  if (tid < 64) {
#pragma unroll
    for (int c = 0; c < 16; ++c) {
      int i = c * 64 + tid;
      bool v = (i < kk) && ((kp[min(i, kk - 1)] >> 32) != 0ULL);
      vmask |= v ? (1u << c) : 0u;
    }
  }
  // staging: x4-batched 16B loads (4 in flight) to hide L2/HBM latency
  {
    const ulonglong2* Tg2 = (const ulonglong2*)Tg;
    ulonglong2* Ts2 = (ulonglong2*)Ts;
    int nv = tw >> 1;
    for (int x = tid; x < nv; x += 1024) {
      int x1i = x + 256, x2i = x + 512, x3i = x + 768;
      ulonglong2 a0 = Tg2[x], a1 = {}, a2 = {}, a3 = {};
      if (x1i < nv) a1 = Tg2[x1i];
      if (x2i < nv) a2 = Tg2[x2i];
      if (x3i < nv) a3 = Tg2[x3i];
      Ts2[x] = a0;
      if (x1i < nv) Ts2[x1i] = a1;
      if (x2i < nv) Ts2[x2i] = a2;
      if (x3i < nv) Ts2[x3i] = a3;
    }
  }
  __syncthreads();
  if (tid >= 64) return;                     // waves 1-3 done (no further barriers)
  int t = tid;
  const int Pt[16] = {0, 1, 4, 7, 12, 17, 24, 31, 40, 49, 60, 71, 84, 97, 112, 127};
  unsigned long long kw[16];
#pragma unroll
  for (int w = 0; w < 16; ++w) kw[w] = 0ULL;
#pragma unroll
  for (int c = 0; c < 16; ++c) {
    if (c * 64 < kk) {
      int base = 64 * Pt[c] + t * ((c + 1) | 1);
      unsigned long long tv[16];
#pragma unroll
      for (int w = 0; w < 16; ++w) tv[w] = Ts[base + w]; // batch reads; w>c garbage, masked
      unsigned long long a = 0;
#pragma unroll
      for (int w = 0; w < 16; ++w) a |= tv[w] & kw[w];   // kw[w]=0 for w>=c
      unsigned long long colT = tv[c];                   // diag word: suppressors j<t in chunk
      bool alive = ((vmask >> c) & 1u) && (a == 0ULL);
      unsigned long long keepm = 0ULL;
      unsigned long long actm = __ballot(alive);
      while (actm) {
        bool cank = alive && ((colT & actm) == 0ULL);    // no alive suppressor below t
        unsigned long long newk = __ballot(cank);
        keepm |= newk;
        alive = alive && !cank && ((colT & newk) == 0ULL);
        actm = __ballot(alive);
      }
      kw[c] = keepm;                                     // static index (unrolled)
    }
  }
  if (t == 0) {
#pragma unroll
    for (int c = 0; c < 16; ++c) keepw[(size_t)p * 16 + c] = kw[c];  // uniform ballot values
  }
}

// ---- merge: 40 blocks = (img,lvl); each compacts all levels (coalesced) but ranks only
// ---- its own level's kept entries (4 interleaved binary searches, short LDS chains) ----
__global__ __launch_bounds__(256) void k_merge(const unsigned long long* keyP, const float* boxP,
                                               const unsigned long long* keepw, float* out) {
  int p = blockIdx.x; int img = p / 5, lvl = p % 5;
  int tid = threadIdx.x;
  __shared__ unsigned long long lkey[5000];   // level l at l*1000: compacted kept keys (desc)
  __shared__ int lpos[5000];                  // original within-image slot
  __shared__ int wp[5][17];                   // per-level word-prefix popcounts
  __shared__ unsigned long long kwS[80];
  for (int x = tid; x < 80; x += 256) {
    kwS[x] = keepw[(size_t)img * 80 + x];     // all 16 words written by k_lvlnms
  }
  __syncthreads();
  if (tid < 5) {
    int acc = 0;
    for (int w = 0; w < 16; ++w) { wp[tid][w] = acc; acc += (int)__popcll(kwS[tid * 16 + w]); }
    wp[tid][16] = acc;
  }
  __syncthreads();
  const unsigned long long* kp = keyP + (size_t)img * K_SEL;
  for (int i = tid; i < K_SEL; i += 256) {
    int l = (i < 4000) ? i / 1000 : 4;
    int li = i - l * 1000;
    unsigned long long wmask = kwS[l * 16 + (li >> 6)];
    if ((wmask >> (li & 63)) & 1ULL) {
      int j = wp[l][li >> 6] + (int)__popcll(wmask & ((1ULL << (li & 63)) - 1ULL));
      lkey[l * 1000 + j] = kp[i];
      lpos[l * 1000 + j] = i;
    }
  }
  __syncthreads();
  const float4* b4 = (const float4*)boxP + (size_t)img * K_SEL;
  float4* out4 = (float4*)out + (size_t)img * 1000;
  int kn = wp[lvl][16];
  for (int j = tid; j < kn; j += 256) {
    unsigned long long key = lkey[lvl * 1000 + j];
    int grank = j;
#pragma unroll
    for (int l2 = 0; l2 < 5; ++l2) {
      if (l2 == lvl) continue;
      int lo = 0, hi = wp[l2][16];
      const unsigned long long* a = &lkey[l2 * 1000];
      while (lo < hi) { int mid = (lo + hi) >> 1; if (a[mid] > key) lo = mid + 1; else hi = mid; }
      grank += lo;                            // count of keys > key in level l2
    }
    if (grank < 1000) out4[grank] = b4[lpos[lvl * 1000 + j]];
  }
  if (lvl == 0) {                             // pad region [KT,1000) has no grank: disjoint
    int KT = wp[0][16] + wp[1][16] + wp[2][16] + wp[3][16] + wp[4][16];
    for (int s = min(KT, 1000) + tid; s < 1000; s += 256)
      out4[s] = make_float4(0.f, 0.f, 0.f, 0.f);          // zero-pad tail
  }
}

extern "C" void kernel_launch(void* const* d_in, const int* in_sizes, int n_in,
                              void* d_out, int out_size, void* d_ws, size_t ws_size,
                              hipStream_t stream) {
  (void)in_sizes; (void)n_in;
  // setup_inputs() dict order is INTERLEAVED: obj_l0, delta_l0, obj_l1, delta_l1, ..., anchors
  P5 obj, del;
  for (int i = 0; i < 5; ++i) {
    obj.p[i] = (const float*)d_in[2 * i];
    del.p[i] = (const float*)d_in[2 * i + 1];
  }
  const float* anchors = (const float*)d_in[10];
  float* out = (float*)d_out;
  char* ws = (char*)d_ws;

  // ws layout (bytes) — nothing needs zero-init
  unsigned* cntB              = (unsigned*)(ws + 0);                   // 5120
  int* Bthr                   = (int*)(ws + 5120);                     // 160 -> 5280
  unsigned long long* candK   = (unsigned long long*)(ws + 8192);      // 5242880 -> 5251072
  float* boxP                 = (float*)(ws + 5548544);                // 610304 -> 6158848
  unsigned long long* keyP    = (unsigned long long*)(ws + 6158848);   // 305152 -> 6464000
  unsigned long long* keepw   = (unsigned long long*)(ws + 6464000);   // 5120 -> 6469120
  unsigned long long* T       = (unsigned long long*)(ws + 6469120);   // 2949120 -> 9418240
  unsigned* phist             = (unsigned*)(ws + 6469120);             // overlay on T (dead before k_lvlmask): 5242880 -> 11712000
  const size_t NEED = 11712000ULL;
  if (ws_size < NEED) { hipMemsetAsync(d_out, 0, (size_t)out_size * 4, stream); return; }

  k_hist    <<<dim3(8, 40), 256, 0, stream>>>(obj, phist);
  k_thresh  <<<40, 256, 0, stream>>>(phist, Bthr);
  k_gather  <<<dim3(32, 40), 256, 0, stream>>>(obj, Bthr, cntB, candK);
  k_seldec  <<<dim3(16, 40), 256, 0, stream>>>(del, anchors, cntB, candK, boxP, keyP);
  k_lvlmask <<<dim3(622, 8), 64, 0, stream>>>(boxP, T);
  k_lvlnms  <<<40, 256, 0, stream>>>(keyP, T, keepw);
  k_merge   <<<40, 256, 0, stream>>>(keyP, boxP, keepw, out);
}